// Round 8
// baseline (466.046 us; speedup 1.0000x reference)
//
#include <hip/hip_runtime.h>
#include <hip/hip_bf16.h>
#include <stdint.h>

#define K_DIM 4096
#define N_DIM 11008
#define GROUP 128

typedef __attribute__((ext_vector_type(8))) __bf16 bf16x8;
typedef __attribute__((ext_vector_type(4))) float f32x4;
typedef __attribute__((ext_vector_type(16))) float f32x16;
typedef __attribute__((address_space(3))) uint8_t lds_u8;
typedef __attribute__((address_space(3))) void lds_void;
typedef __attribute__((address_space(1))) const void g_void;

static __device__ inline __bf16 f2bf(float f) { return (__bf16)f; }

// ================= prepass 1: x fp32 -> bf16 ([M][K] row-major) =================
__global__ __launch_bounds__(256) void cvt_x_kernel(const float* __restrict__ x,
                                                    __bf16* __restrict__ xb, int total8) {
    int t = blockIdx.x * 256 + threadIdx.x;
    if (t >= total8) return;
    f32x4 a0 = *(const f32x4*)(x + (size_t)t * 8);
    f32x4 a1 = *(const f32x4*)(x + (size_t)t * 8 + 4);
    bf16x8 v;
    #pragma unroll
    for (int j = 0; j < 4; ++j) { v[j] = f2bf(a0[j]); v[j + 4] = f2bf(a1[j]); }
    *(bf16x8*)(xb + (size_t)t * 8) = v;
}

// ============ prepass 2: dequant W int4 -> bf16, stored TRANSPOSED [N][K] ============
__global__ __launch_bounds__(256) void dequant_w_kernel(const int* __restrict__ qw,
                                                        const int* __restrict__ qz,
                                                        const float* __restrict__ sc,
                                                        __bf16* __restrict__ wb) {
    const int n   = blockIdx.x * 256 + threadIdx.x;
    const int kb0 = blockIdx.y * 8;
    const int g   = blockIdx.y >> 1;
    const float s   = sc[(size_t)g * N_DIM + n];
    const float nzs = -(float)((qz[(size_t)g * (N_DIM / 8) + (n >> 3)] >> ((n & 7) * 4)) & 15) * s;
    #pragma unroll
    for (int j = 0; j < 8; ++j) {
        const int w = qw[(size_t)(kb0 + j) * N_DIM + n];
        bf16x8 v;
        #pragma unroll
        for (int b = 0; b < 8; ++b)
            v[b] = f2bf(fmaf((float)((w >> (4 * b)) & 15), s, nzs));
        *(bf16x8*)(wb + (size_t)n * K_DIM + (size_t)(kb0 + j) * 8) = v;
    }
}

// ================= main GEMM: 256x256, BK=64, 8 waves, r3 coarse 3-phase =================
// r7 structure (32x32x16 MFMA) with the bank-conflict FIX: storage/read permutation
// perm(row) = (row&7) ^ (((row>>3)&3)<<1), so every consecutive 8-lane group sweeps
// all 8 chunk positions exactly once (the property that made the 16x16 pattern
// conflict-free; r7's perm=row&7 left lanes {l,l+8,l+16,l+24} on one bank group).
// A/B frag: row/col = lane&31, k = (lane>>5)*8 + i. C/D: col=lane&31,
// row = (reg&3)+8*(reg>>2)+4*(lane>>5)  [m74/m101, r7-validated].
#define BM2 256
#define BN2 256
#define BK2 64
#define NT  (K_DIM / BK2)   // 64

__global__ __launch_bounds__(512, 2) void gemm256_kernel(
    const __bf16* __restrict__ xb, const __bf16* __restrict__ wb,
    const float* __restrict__ bias, float* __restrict__ out)
{
    __shared__ __align__(16) __bf16 As[2][BM2 * BK2];   // 2 x 32 KiB
    __shared__ __align__(16) __bf16 Bs[2][BN2 * BK2];   // 2 x 32 KiB

    const int tid  = threadIdx.x;
    const int lane = tid & 63;
    const int wid  = tid >> 6;             // 8 waves: 2(M) x 4(N)
    const int wm = (wid >> 2) * 128;
    const int wn = (wid & 3) * 64;

    // XCD-bijective swizzle: grid 688 = 8 * 86
    const int bid = blockIdx.x;
    const int wg  = (bid & 7) * 86 + (bid >> 3);
    const int m0 = (wg / 43) * BM2;
    const int n0 = (wg % 43) * BN2;

    // staging: chunk ch = l*512+tid; row = ch>>3;
    // stored position p=ch&7 holds global chunk p ^ perm(row),
    // perm(row) = (row&7) ^ (((row>>3)&3)<<1)
    const __bf16* pa[4];
    const __bf16* pb[4];
    int chk[4];
    #pragma unroll
    for (int l = 0; l < 4; ++l) {
        const int ch  = l * 512 + tid;
        const int row = ch >> 3;
        const int pr  = (row & 7) ^ (((row >> 3) & 3) << 1);
        const int g   = (ch & 7) ^ pr;
        chk[l] = ch;
        pa[l] = xb + (size_t)(m0 + row) * K_DIM + g * 8;
        pb[l] = wb + (size_t)(n0 + row) * K_DIM + g * 8;
    }
    lds_u8* baseA = (lds_u8*)&As[0][0];
    lds_u8* baseB = (lds_u8*)&Bs[0][0];

    auto STAGE = [&](int buf, int kofs) {   // full tile: 4 A + 4 B loads per thread
        lds_u8* dA_ = baseA + buf * (BM2 * BK2 * 2);
        lds_u8* dB_ = baseB + buf * (BN2 * BK2 * 2);
        #pragma unroll
        for (int l = 0; l < 4; ++l)
            __builtin_amdgcn_global_load_lds((g_void*)(pa[l] + kofs),
                                             (lds_void*)(dA_ + chk[l] * 16), 16, 0, 0);
        #pragma unroll
        for (int l = 0; l < 4; ++l)
            __builtin_amdgcn_global_load_lds((g_void*)(pb[l] + kofs),
                                             (lds_void*)(dB_ + chk[l] * 16), 16, 0, 0);
    };

    // fragment addressing: frag rows = 32*k + (lane&31) -> perm reduces to lane constant
    const int fr  = lane & 31;
    const int fc  = lane >> 5;             // 0..1
    const int swz = (lane & 7) ^ (((lane >> 3) & 3) << 1);
    int cofs[4];
    #pragma unroll
    for (int ks = 0; ks < 4; ++ks)
        cofs[ks] = ((ks * 2 + fc) ^ swz) * 8;
    const int rowoffA = (wm + fr) * BK2;   // elems
    const int rowoffB = (wn + fr) * BK2;

    f32x16 acc[4][2];
    #pragma unroll
    for (int m = 0; m < 4; ++m)
        #pragma unroll
        for (int n = 0; n < 2; ++n)
            #pragma unroll
            for (int r = 0; r < 16; ++r) acc[m][n][r] = 0.f;

    // ---- prologue: tiles 0 and 1 in flight, wait for tile 0 ----
    STAGE(0, 0);
    STAGE(1, BK2);
    asm volatile("s_waitcnt vmcnt(8)" ::: "memory");
    __builtin_amdgcn_sched_barrier(0);
    __builtin_amdgcn_s_barrier();
    __builtin_amdgcn_sched_barrier(0);

    for (int t = 0; t < NT; ++t) {
        const int cur = t & 1;
        const __bf16* ra = &As[0][0] + cur * (BM2 * BK2) + rowoffA;
        const __bf16* rb = &Bs[0][0] + cur * (BN2 * BK2) + rowoffB;
        bf16x8 aR[8], a2[8], bR[8];   // aR: mb0(0-3),mb1(4-7); a2: mb2,mb3; bR: nb0(0-3),nb1(4-7)

        // ---- phase A: read bR(nb0) + aR(mb0,mb1); MFMA (mb0,1 x nb0) ----
        #pragma unroll
        for (int ks = 0; ks < 4; ++ks)
            bR[ks] = *(const bf16x8*)(rb + cofs[ks]);                    // nb0: rows wn+fr
        #pragma unroll
        for (int mb = 0; mb < 2; ++mb)
            #pragma unroll
            for (int ks = 0; ks < 4; ++ks)
                aR[mb * 4 + ks] = *(const bf16x8*)(ra + mb * 2048 + cofs[ks]);   // 32 rows * 64
        __builtin_amdgcn_s_setprio(1);
        #pragma unroll
        for (int mb = 0; mb < 2; ++mb)
            #pragma unroll
            for (int ks = 0; ks < 4; ++ks)
                acc[mb][0] = __builtin_amdgcn_mfma_f32_32x32x16_bf16(
                    aR[mb * 4 + ks], bR[ks], acc[mb][0], 0, 0, 0);
        __builtin_amdgcn_s_setprio(0);

        // ---- phase B: read bR(nb1); MFMA (mb0,1 x nb1) ----
        #pragma unroll
        for (int ks = 0; ks < 4; ++ks)
            bR[4 + ks] = *(const bf16x8*)(rb + 2048 + cofs[ks]);         // nb1: rows wn+32+fr
        __builtin_amdgcn_s_setprio(1);
        #pragma unroll
        for (int mb = 0; mb < 2; ++mb)
            #pragma unroll
            for (int ks = 0; ks < 4; ++ks)
                acc[mb][1] = __builtin_amdgcn_mfma_f32_32x32x16_bf16(
                    aR[mb * 4 + ks], bR[4 + ks], acc[mb][1], 0, 0, 0);
        __builtin_amdgcn_s_setprio(0);

        // ---- phase C: read a2(mb2,3); fence; barrier; prefetch t+2; MFMA rest ----
        #pragma unroll
        for (int mb = 0; mb < 2; ++mb)
            #pragma unroll
            for (int ks = 0; ks < 4; ++ks)
                a2[mb * 4 + ks] = *(const bf16x8*)(ra + (mb + 2) * 2048 + cofs[ks]);
        asm volatile("s_waitcnt lgkmcnt(0)" ::: "memory");   // my reads of buf[cur] done
        __builtin_amdgcn_sched_barrier(0);
        __builtin_amdgcn_s_barrier();                        // all waves done reading buf[cur]
        __builtin_amdgcn_sched_barrier(0);
        if (t + 2 < NT) STAGE(cur, (t + 2) * BK2);           // overwrite buf[cur] with tile t+2

        __builtin_amdgcn_s_setprio(1);
        #pragma unroll
        for (int mb = 0; mb < 2; ++mb)
            #pragma unroll
            for (int nb = 0; nb < 2; ++nb)
                #pragma unroll
                for (int ks = 0; ks < 4; ++ks)
                    acc[mb + 2][nb] = __builtin_amdgcn_mfma_f32_32x32x16_bf16(
                        a2[mb * 4 + ks], bR[nb * 4 + ks], acc[mb + 2][nb], 0, 0, 0);
        __builtin_amdgcn_s_setprio(0);

        // tile t+1 (8 oldest outstanding loads) must be complete before next iter
        if (t + 2 < NT) { asm volatile("s_waitcnt vmcnt(8)" ::: "memory"); }
        else            { asm volatile("s_waitcnt vmcnt(0)" ::: "memory"); }
        __builtin_amdgcn_sched_barrier(0);
        __builtin_amdgcn_s_barrier();
        __builtin_amdgcn_sched_barrier(0);
    }

    // ---- epilogue: C/D layout col=lane&31, row=(reg&3)+8*(reg>>2)+4*(lane>>5) ----
    const int cn    = lane & 31;
    const int rbase = 4 * (lane >> 5);
    #pragma unroll
    for (int nb = 0; nb < 2; ++nb) {
        const int col = n0 + wn + nb * 32 + cn;
        const float bv = bias[col];
        #pragma unroll
        for (int mb = 0; mb < 4; ++mb) {
            const int rtop = m0 + wm + mb * 32 + rbase;
            #pragma unroll
            for (int reg = 0; reg < 16; ++reg) {
                const int row = rtop + (reg & 3) + 8 * (reg >> 2);
                out[(size_t)row * N_DIM + col] = acc[mb][nb][reg] + bv;
            }
        }
    }
}

// ================= fallback: fused kernel (if ws too small) =================
#define FBM 128
#define FBN 128
#define FBK 32
#define FLDSS 40
__global__ __launch_bounds__(256) void gptq_gemm_fused_kernel(
    const float* __restrict__ x, const int* __restrict__ qw, const int* __restrict__ qz,
    const float* __restrict__ sc, const float* __restrict__ bias, float* __restrict__ out)
{
    __shared__ __align__(16) __bf16 Asm[FBM][FLDSS];
    __shared__ __align__(16) __bf16 Bsm[FBN][FLDSS];
    const int tid = threadIdx.x, lane = tid & 63, wid = tid >> 6;
    const int m0 = blockIdx.y * FBM, n0 = blockIdx.x * FBN;
    const int wm = (wid >> 1) * 64, wn = (wid & 1) * 64;
    f32x4 acc[4][4];
    #pragma unroll
    for (int i = 0; i < 4; ++i)
        #pragma unroll
        for (int j = 0; j < 4; ++j) acc[i][j] = (f32x4){0.f, 0.f, 0.f, 0.f};
    const int a_m = tid >> 2, a_h = tid & 3;
    const int b_n = tid & 127, b_k8 = tid >> 7;
    const int ng = n0 + b_n, zsh = (ng & 7) * 4;
    const int fr = lane & 15, fc = lane >> 4;
    for (int k0 = 0; k0 < K_DIM; k0 += FBK) {
        const int g = k0 >> 7;
        const float* xa = x + (size_t)(m0 + a_m) * K_DIM + k0 + a_h * 8;
        f32x4 a0 = *(const f32x4*)xa;
        f32x4 a1 = *(const f32x4*)(xa + 4);
        const float* xbp = xa + (size_t)64 * K_DIM;
        f32x4 a2 = *(const f32x4*)xbp;
        f32x4 a3 = *(const f32x4*)(xbp + 4);
        const int kb = (k0 >> 3) + b_k8;
        const int w0 = qw[(size_t)kb * N_DIM + ng];
        const int w1 = qw[(size_t)(kb + 2) * N_DIM + ng];
        const float s = sc[(size_t)g * N_DIM + ng];
        const float nzs = -(float)((qz[(size_t)g * (N_DIM / 8) + (ng >> 3)] >> zsh) & 15) * s;
        __syncthreads();
        bf16x8 av0, av1;
        #pragma unroll
        for (int j = 0; j < 4; ++j) {
            av0[j] = f2bf(a0[j]); av0[j + 4] = f2bf(a1[j]);
            av1[j] = f2bf(a2[j]); av1[j + 4] = f2bf(a3[j]);
        }
        *(bf16x8*)&Asm[a_m][a_h * 8] = av0;
        *(bf16x8*)&Asm[a_m + 64][a_h * 8] = av1;
        bf16x8 bv0, bv1;
        #pragma unroll
        for (int j = 0; j < 8; ++j) {
            bv0[j] = f2bf(fmaf((float)((w0 >> (4 * j)) & 15), s, nzs));
            bv1[j] = f2bf(fmaf((float)((w1 >> (4 * j)) & 15), s, nzs));
        }
        *(bf16x8*)&Bsm[b_n][b_k8 * 8] = bv0;
        *(bf16x8*)&Bsm[b_n][(b_k8 + 2) * 8] = bv1;
        __syncthreads();
        bf16x8 af[4], bfr[4];
        #pragma unroll
        for (int i = 0; i < 4; ++i) af[i] = *(const bf16x8*)&Asm[wm + i * 16 + fr][fc * 8];
        #pragma unroll
        for (int j = 0; j < 4; ++j) bfr[j] = *(const bf16x8*)&Bsm[wn + j * 16 + fr][fc * 8];
        #pragma unroll
        for (int i = 0; i < 4; ++i)
            #pragma unroll
            for (int j = 0; j < 4; ++j)
                acc[i][j] = __builtin_amdgcn_mfma_f32_16x16x32_bf16(af[i], bfr[j], acc[i][j], 0, 0, 0);
    }
    const int cn = lane & 15, cr4 = (lane >> 4) * 4;
    #pragma unroll
    for (int j = 0; j < 4; ++j) {
        const int col = n0 + wn + j * 16 + cn;
        const float bv = bias[col];
        #pragma unroll
        for (int i = 0; i < 4; ++i) {
            const int row = m0 + wm + i * 16 + cr4;
            #pragma unroll
            for (int r = 0; r < 4; ++r)
                out[(size_t)(row + r) * N_DIM + col] = acc[i][j][r] + bv;
        }
    }
}

extern "C" void kernel_launch(void* const* d_in, const int* in_sizes, int n_in,
                              void* d_out, int out_size, void* d_ws, size_t ws_size,
                              hipStream_t stream) {
    const float* x    = (const float*)d_in[0];
    const int*   qw   = (const int*)d_in[1];
    const int*   qz   = (const int*)d_in[2];
    const float* sc   = (const float*)d_in[3];
    const float* bias = (const float*)d_in[4];
    float* out = (float*)d_out;
    const int M = in_sizes[0] / K_DIM;   // 4096

    const size_t xb_bytes = (size_t)M * K_DIM * sizeof(__bf16);        // 32 MiB
    const size_t wb_bytes = (size_t)N_DIM * K_DIM * sizeof(__bf16);    // 86 MiB
    if (ws_size >= xb_bytes + wb_bytes && (M % BM2) == 0) {
        __bf16* xb = (__bf16*)d_ws;
        __bf16* wb = (__bf16*)((uint8_t*)d_ws + xb_bytes);
        const int total8 = M * K_DIM / 8;
        cvt_x_kernel<<<dim3(total8 / 256), dim3(256), 0, stream>>>(x, xb, total8);
        dequant_w_kernel<<<dim3(N_DIM / 256, K_DIM / 8 / 8), dim3(256), 0, stream>>>(qw, qz, sc, wb);
        const int nblocks = (N_DIM / BN2) * (M / BM2);   // 43 * 16 = 688
        gemm256_kernel<<<dim3(nblocks), dim3(512), 0, stream>>>(xb, wb, bias, out);
    } else {
        gptq_gemm_fused_kernel<<<dim3(N_DIM / FBN, M / FBM), dim3(256), 0, stream>>>(x, qw, qz, sc, bias, out);
    }
}

// Round 9
// 417.107 us; speedup vs baseline: 1.1173x; 1.1173x over previous
//
#include <hip/hip_runtime.h>
#include <hip/hip_bf16.h>
#include <stdint.h>

#define K_DIM 4096
#define N_DIM 11008
#define GROUP 128

typedef __attribute__((ext_vector_type(8))) __bf16 bf16x8;
typedef __attribute__((ext_vector_type(4))) float f32x4;
typedef __attribute__((address_space(3))) uint8_t lds_u8;
typedef __attribute__((address_space(3))) void lds_void;
typedef __attribute__((address_space(1))) const void g_void;

static __device__ inline __bf16 f2bf(float f) { return (__bf16)f; }

// ================= prepass 1: x fp32 -> bf16 ([M][K] row-major) =================
__global__ __launch_bounds__(256) void cvt_x_kernel(const float* __restrict__ x,
                                                    __bf16* __restrict__ xb, int total8) {
    int t = blockIdx.x * 256 + threadIdx.x;
    if (t >= total8) return;
    f32x4 a0 = *(const f32x4*)(x + (size_t)t * 8);
    f32x4 a1 = *(const f32x4*)(x + (size_t)t * 8 + 4);
    bf16x8 v;
    #pragma unroll
    for (int j = 0; j < 4; ++j) { v[j] = f2bf(a0[j]); v[j + 4] = f2bf(a1[j]); }
    *(bf16x8*)(xb + (size_t)t * 8) = v;
}

// ============ prepass 2: dequant W int4 -> bf16, stored TRANSPOSED [N][K] ============
__global__ __launch_bounds__(256) void dequant_w_kernel(const int* __restrict__ qw,
                                                        const int* __restrict__ qz,
                                                        const float* __restrict__ sc,
                                                        __bf16* __restrict__ wb) {
    const int n   = blockIdx.x * 256 + threadIdx.x;
    const int kb0 = blockIdx.y * 8;
    const int g   = blockIdx.y >> 1;
    const float s   = sc[(size_t)g * N_DIM + n];
    const float nzs = -(float)((qz[(size_t)g * (N_DIM / 8) + (n >> 3)] >> ((n & 7) * 4)) & 15) * s;
    #pragma unroll
    for (int j = 0; j < 8; ++j) {
        const int w = qw[(size_t)(kb0 + j) * N_DIM + n];
        bf16x8 v;
        #pragma unroll
        for (int b = 0; b < 8; ++b)
            v[b] = f2bf(fmaf((float)((w >> (4 * b)) & 15), s, nzs));
        *(bf16x8*)(wb + (size_t)n * K_DIM + (size_t)(kb0 + j) * 8) = v;
    }
}

// ================= main GEMM: 256x256 tile, BK=64, 8 waves, deep pipeline =================
// EXACT r3 kernel (session best: GEMM 372-383us, 985 TF): coarse 3-phase, 2 barriers/K-tile,
// fat read bursts (12/4/8 ds_read_b128), counted vmcnt(8), 16x16x32 MFMA.
#define BM2 256
#define BN2 256
#define BK2 64
#define NT  (K_DIM / BK2)   // 64

__global__ __launch_bounds__(512, 2) void gemm256_kernel(
    const __bf16* __restrict__ xb, const __bf16* __restrict__ wb,
    const float* __restrict__ bias, float* __restrict__ out)
{
    __shared__ __align__(16) __bf16 As[2][BM2 * BK2];   // 2 x 32 KiB
    __shared__ __align__(16) __bf16 Bs[2][BN2 * BK2];   // 2 x 32 KiB

    const int tid  = threadIdx.x;
    const int lane = tid & 63;
    const int wid  = tid >> 6;             // 8 waves: 2(M) x 4(N)
    const int wm = (wid >> 2) * 128;
    const int wn = (wid & 3) * 64;

    // XCD-bijective swizzle: grid 688 = 8 * 86
    const int bid = blockIdx.x;
    const int wg  = (bid & 7) * 86 + (bid >> 3);
    const int m0 = (wg / 43) * BM2;
    const int n0 = (wg % 43) * BN2;

    // ---- staging: 4 x 16B chunks per thread per operand per K-tile ----
    const __bf16* pa[4];
    const __bf16* pb[4];
    int chk[4];
    #pragma unroll
    for (int l = 0; l < 4; ++l) {
        const int ch  = l * 512 + tid;         // 0..2047
        const int row = ch >> 3;
        const int g   = (ch & 7) ^ (row & 7);  // involution per row
        chk[l] = ch;
        pa[l] = xb + (size_t)(m0 + row) * K_DIM + g * 8;
        pb[l] = wb + (size_t)(n0 + row) * K_DIM + g * 8;
    }
    lds_u8* baseA = (lds_u8*)&As[0][0];
    lds_u8* baseB = (lds_u8*)&Bs[0][0];

    auto STAGE = [&](int buf, int kofs) {
        lds_u8* dA_ = baseA + buf * (BM2 * BK2 * 2);
        lds_u8* dB_ = baseB + buf * (BN2 * BK2 * 2);
        #pragma unroll
        for (int l = 0; l < 4; ++l)
            __builtin_amdgcn_global_load_lds((g_void*)(pa[l] + kofs),
                                             (lds_void*)(dA_ + chk[l] * 16), 16, 0, 0);
        #pragma unroll
        for (int l = 0; l < 4; ++l)
            __builtin_amdgcn_global_load_lds((g_void*)(pb[l] + kofs),
                                             (lds_void*)(dB_ + chk[l] * 16), 16, 0, 0);
    };

    // ---- fragment read addressing (swizzle folded in) ----
    const int fr  = lane & 15;
    const int fc  = lane >> 4;
    const int swz = fr & 7;
    const int col0 = (fc ^ swz) * 8;           // kk = 0
    const int col1 = ((4 + fc) ^ swz) * 8;     // kk = 1
    const int rowoffA = (wm + fr) * BK2;       // elems
    const int rowoffB = (wn + fr) * BK2;

    f32x4 acc[8][4];
    #pragma unroll
    for (int m = 0; m < 8; ++m)
        #pragma unroll
        for (int n = 0; n < 4; ++n) acc[m][n] = (f32x4){0.f, 0.f, 0.f, 0.f};

    // ---- prologue: tiles 0 and 1 in flight, wait for tile 0 ----
    STAGE(0, 0);
    STAGE(1, BK2);
    asm volatile("s_waitcnt vmcnt(8)" ::: "memory");
    __builtin_amdgcn_sched_barrier(0);
    __builtin_amdgcn_s_barrier();
    __builtin_amdgcn_sched_barrier(0);

    for (int t = 0; t < NT; ++t) {
        const int cur = t & 1;
        const __bf16* ra = &As[0][0] + cur * (BM2 * BK2) + rowoffA;
        const __bf16* rb = &Bs[0][0] + cur * (BN2 * BK2) + rowoffB;
        bf16x8 aR[8], bR[8], a2[8];

        // ---- phase A: b(n=0,1) + a(m=0..3) reads, MFMA quadrant (mh0,nh0) ----
        #pragma unroll
        for (int n = 0; n < 2; ++n) {
            bR[n * 2 + 0] = *(const bf16x8*)(rb + n * 1024 + col0);
            bR[n * 2 + 1] = *(const bf16x8*)(rb + n * 1024 + col1);
        }
        #pragma unroll
        for (int m = 0; m < 4; ++m) {
            aR[m * 2 + 0] = *(const bf16x8*)(ra + m * 1024 + col0);
            aR[m * 2 + 1] = *(const bf16x8*)(ra + m * 1024 + col1);
        }
        __builtin_amdgcn_s_setprio(1);
        #pragma unroll
        for (int m = 0; m < 4; ++m)
            #pragma unroll
            for (int n = 0; n < 2; ++n)
                #pragma unroll
                for (int kk = 0; kk < 2; ++kk)
                    acc[m][n] = __builtin_amdgcn_mfma_f32_16x16x32_bf16(
                        aR[m * 2 + kk], bR[n * 2 + kk], acc[m][n], 0, 0, 0);
        __builtin_amdgcn_s_setprio(0);

        // ---- phase B: b(n=2,3) reads, MFMA quadrant (mh0,nh1) ----
        #pragma unroll
        for (int n = 2; n < 4; ++n) {
            bR[n * 2 + 0] = *(const bf16x8*)(rb + n * 1024 + col0);
            bR[n * 2 + 1] = *(const bf16x8*)(rb + n * 1024 + col1);
        }
        __builtin_amdgcn_s_setprio(1);
        #pragma unroll
        for (int m = 0; m < 4; ++m)
            #pragma unroll
            for (int n = 2; n < 4; ++n)
                #pragma unroll
                for (int kk = 0; kk < 2; ++kk)
                    acc[m][n] = __builtin_amdgcn_mfma_f32_16x16x32_bf16(
                        aR[m * 2 + kk], bR[n * 2 + kk], acc[m][n], 0, 0, 0);
        __builtin_amdgcn_s_setprio(0);

        // ---- phase C: a(m=4..7) reads; fence reads; barrier; prefetch t+2; MFMA rest ----
        #pragma unroll
        for (int m = 0; m < 4; ++m) {
            a2[m * 2 + 0] = *(const bf16x8*)(ra + (m + 4) * 1024 + col0);
            a2[m * 2 + 1] = *(const bf16x8*)(ra + (m + 4) * 1024 + col1);
        }
        asm volatile("s_waitcnt lgkmcnt(0)" ::: "memory");   // my reads of buf[cur] done
        __builtin_amdgcn_sched_barrier(0);
        __builtin_amdgcn_s_barrier();                        // all waves done reading buf[cur]
        __builtin_amdgcn_sched_barrier(0);
        if (t + 2 < NT) STAGE(cur, (t + 2) * BK2);           // overwrite buf[cur] with tile t+2

        __builtin_amdgcn_s_setprio(1);
        #pragma unroll
        for (int m = 0; m < 4; ++m)
            #pragma unroll
            for (int n = 2; n < 4; ++n)
                #pragma unroll
                for (int kk = 0; kk < 2; ++kk)
                    acc[m + 4][n] = __builtin_amdgcn_mfma_f32_16x16x32_bf16(
                        a2[m * 2 + kk], bR[n * 2 + kk], acc[m + 4][n], 0, 0, 0);
        #pragma unroll
        for (int m = 0; m < 4; ++m)
            #pragma unroll
            for (int n = 0; n < 2; ++n)
                #pragma unroll
                for (int kk = 0; kk < 2; ++kk)
                    acc[m + 4][n] = __builtin_amdgcn_mfma_f32_16x16x32_bf16(
                        a2[m * 2 + kk], bR[n * 2 + kk], acc[m + 4][n], 0, 0, 0);
        __builtin_amdgcn_s_setprio(0);

        // tile t+1 (8 oldest outstanding loads) must be complete before next iter
        if (t + 2 < NT) { asm volatile("s_waitcnt vmcnt(8)" ::: "memory"); }
        else            { asm volatile("s_waitcnt vmcnt(0)" ::: "memory"); }
        __builtin_amdgcn_sched_barrier(0);
        __builtin_amdgcn_s_barrier();
        __builtin_amdgcn_sched_barrier(0);
    }

    // ---- epilogue: C/D layout col=lane&15, row=(lane>>4)*4+r ----
    const int cn  = lane & 15;
    const int cr4 = (lane >> 4) * 4;
    #pragma unroll
    for (int n = 0; n < 4; ++n) {
        const int col = n0 + wn + n * 16 + cn;
        const float bv = bias[col];
        #pragma unroll
        for (int m = 0; m < 8; ++m) {
            const int row = m0 + wm + m * 16 + cr4;
            #pragma unroll
            for (int r = 0; r < 4; ++r)
                out[(size_t)(row + r) * N_DIM + col] = acc[m][n][r] + bv;
        }
    }
}

// ================= fallback: round-1 fused kernel (if ws too small) =================
#define FBM 128
#define FBN 128
#define FBK 32
#define FLDSS 40
__global__ __launch_bounds__(256) void gptq_gemm_fused_kernel(
    const float* __restrict__ x, const int* __restrict__ qw, const int* __restrict__ qz,
    const float* __restrict__ sc, const float* __restrict__ bias, float* __restrict__ out)
{
    __shared__ __align__(16) __bf16 Asm[FBM][FLDSS];
    __shared__ __align__(16) __bf16 Bsm[FBN][FLDSS];
    const int tid = threadIdx.x, lane = tid & 63, wid = tid >> 6;
    const int m0 = blockIdx.y * FBM, n0 = blockIdx.x * FBN;
    const int wm = (wid >> 1) * 64, wn = (wid & 1) * 64;
    f32x4 acc[4][4];
    #pragma unroll
    for (int i = 0; i < 4; ++i)
        #pragma unroll
        for (int j = 0; j < 4; ++j) acc[i][j] = (f32x4){0.f, 0.f, 0.f, 0.f};
    const int a_m = tid >> 2, a_h = tid & 3;
    const int b_n = tid & 127, b_k8 = tid >> 7;
    const int ng = n0 + b_n, zsh = (ng & 7) * 4;
    const int fr = lane & 15, fc = lane >> 4;
    for (int k0 = 0; k0 < K_DIM; k0 += FBK) {
        const int g = k0 >> 7;
        const float* xa = x + (size_t)(m0 + a_m) * K_DIM + k0 + a_h * 8;
        f32x4 a0 = *(const f32x4*)xa;
        f32x4 a1 = *(const f32x4*)(xa + 4);
        const float* xbp = xa + (size_t)64 * K_DIM;
        f32x4 a2 = *(const f32x4*)xbp;
        f32x4 a3 = *(const f32x4*)(xbp + 4);
        const int kb = (k0 >> 3) + b_k8;
        const int w0 = qw[(size_t)kb * N_DIM + ng];
        const int w1 = qw[(size_t)(kb + 2) * N_DIM + ng];
        const float s = sc[(size_t)g * N_DIM + ng];
        const float nzs = -(float)((qz[(size_t)g * (N_DIM / 8) + (ng >> 3)] >> zsh) & 15) * s;
        __syncthreads();
        bf16x8 av0, av1;
        #pragma unroll
        for (int j = 0; j < 4; ++j) {
            av0[j] = f2bf(a0[j]); av0[j + 4] = f2bf(a1[j]);
            av1[j] = f2bf(a2[j]); av1[j + 4] = f2bf(a3[j]);
        }
        *(bf16x8*)&Asm[a_m][a_h * 8] = av0;
        *(bf16x8*)&Asm[a_m + 64][a_h * 8] = av1;
        bf16x8 bv0, bv1;
        #pragma unroll
        for (int j = 0; j < 8; ++j) {
            bv0[j] = f2bf(fmaf((float)((w0 >> (4 * j)) & 15), s, nzs));
            bv1[j] = f2bf(fmaf((float)((w1 >> (4 * j)) & 15), s, nzs));
        }
        *(bf16x8*)&Bsm[b_n][b_k8 * 8] = bv0;
        *(bf16x8*)&Bsm[b_n][(b_k8 + 2) * 8] = bv1;
        __syncthreads();
        bf16x8 af[4], bfr[4];
        #pragma unroll
        for (int i = 0; i < 4; ++i) af[i] = *(const bf16x8*)&Asm[wm + i * 16 + fr][fc * 8];
        #pragma unroll
        for (int j = 0; j < 4; ++j) bfr[j] = *(const bf16x8*)&Bsm[wn + j * 16 + fr][fc * 8];
        #pragma unroll
        for (int i = 0; i < 4; ++i)
            #pragma unroll
            for (int j = 0; j < 4; ++j)
                acc[i][j] = __builtin_amdgcn_mfma_f32_16x16x32_bf16(af[i], bfr[j], acc[i][j], 0, 0, 0);
    }
    const int cn = lane & 15, cr4 = (lane >> 4) * 4;
    #pragma unroll
    for (int j = 0; j < 4; ++j) {
        const int col = n0 + wn + j * 16 + cn;
        const float bv = bias[col];
        #pragma unroll
        for (int i = 0; i < 4; ++i) {
            const int row = m0 + wm + i * 16 + cr4;
            #pragma unroll
            for (int r = 0; r < 4; ++r)
                out[(size_t)(row + r) * N_DIM + col] = acc[i][j][r] + bv;
        }
    }
}

extern "C" void kernel_launch(void* const* d_in, const int* in_sizes, int n_in,
                              void* d_out, int out_size, void* d_ws, size_t ws_size,
                              hipStream_t stream) {
    const float* x    = (const float*)d_in[0];
    const int*   qw   = (const int*)d_in[1];
    const int*   qz   = (const int*)d_in[2];
    const float* sc   = (const float*)d_in[3];
    const float* bias = (const float*)d_in[4];
    float* out = (float*)d_out;
    const int M = in_sizes[0] / K_DIM;   // 4096

    const size_t xb_bytes = (size_t)M * K_DIM * sizeof(__bf16);        // 32 MiB
    const size_t wb_bytes = (size_t)N_DIM * K_DIM * sizeof(__bf16);    // 86 MiB
    if (ws_size >= xb_bytes + wb_bytes && (M % BM2) == 0) {
        __bf16* xb = (__bf16*)d_ws;
        __bf16* wb = (__bf16*)((uint8_t*)d_ws + xb_bytes);
        const int total8 = M * K_DIM / 8;
        cvt_x_kernel<<<dim3(total8 / 256), dim3(256), 0, stream>>>(x, xb, total8);
        dequant_w_kernel<<<dim3(N_DIM / 256, K_DIM / 8 / 8), dim3(256), 0, stream>>>(qw, qz, sc, wb);
        const int nblocks = (N_DIM / BN2) * (M / BM2);   // 43 * 16 = 688
        gemm256_kernel<<<dim3(nblocks), dim3(512), 0, stream>>>(xb, wb, bias, out);
    } else {
        gptq_gemm_fused_kernel<<<dim3(N_DIM / FBN, M / FBM), dim3(256), 0, stream>>>(x, qw, qz, sc, bias, out);
    }
}

// Round 10
// 416.091 us; speedup vs baseline: 1.1201x; 1.0024x over previous
//
#include <hip/hip_runtime.h>
#include <hip/hip_bf16.h>
#include <stdint.h>

#define K_DIM 4096
#define N_DIM 11008
#define GROUP 128

typedef __attribute__((ext_vector_type(8))) __bf16 bf16x8;
typedef __attribute__((ext_vector_type(4))) float f32x4;
typedef __attribute__((address_space(3))) uint8_t lds_u8;
typedef __attribute__((address_space(3))) void lds_void;
typedef __attribute__((address_space(1))) const void g_void;

static __device__ inline __bf16 f2bf(float f) { return (__bf16)f; }

// ================= prepass 1: x fp32 -> bf16 ([M][K] row-major) =================
__global__ __launch_bounds__(256) void cvt_x_kernel(const float* __restrict__ x,
                                                    __bf16* __restrict__ xb, int total8) {
    int t = blockIdx.x * 256 + threadIdx.x;
    if (t >= total8) return;
    f32x4 a0 = *(const f32x4*)(x + (size_t)t * 8);
    f32x4 a1 = *(const f32x4*)(x + (size_t)t * 8 + 4);
    bf16x8 v;
    #pragma unroll
    for (int j = 0; j < 4; ++j) { v[j] = f2bf(a0[j]); v[j + 4] = f2bf(a1[j]); }
    *(bf16x8*)(xb + (size_t)t * 8) = v;
}

// ============ prepass 2: dequant W int4 -> bf16, stored TRANSPOSED [N][K] ============
__global__ __launch_bounds__(256) void dequant_w_kernel(const int* __restrict__ qw,
                                                        const int* __restrict__ qz,
                                                        const float* __restrict__ sc,
                                                        __bf16* __restrict__ wb) {
    const int n   = blockIdx.x * 256 + threadIdx.x;
    const int kb0 = blockIdx.y * 8;
    const int g   = blockIdx.y >> 1;
    const float s   = sc[(size_t)g * N_DIM + n];
    const float nzs = -(float)((qz[(size_t)g * (N_DIM / 8) + (n >> 3)] >> ((n & 7) * 4)) & 15) * s;
    #pragma unroll
    for (int j = 0; j < 8; ++j) {
        const int w = qw[(size_t)(kb0 + j) * N_DIM + n];
        bf16x8 v;
        #pragma unroll
        for (int b = 0; b < 8; ++b)
            v[b] = f2bf(fmaf((float)((w >> (4 * b)) & 15), s, nzs));
        *(bf16x8*)(wb + (size_t)n * K_DIM + (size_t)(kb0 + j) * 8) = v;
    }
}

// ================= main GEMM: 256x256 tile, BK=64, 8 waves =================
// r3/r9 skeleton (2 barriers/K-tile, counted vmcnt(8), 16x16x32) with ONE change:
// all 24 ds_read_b128 hoisted to the tile top (phase-A operands first), so phase
// B/C MFMA never wait on LDS and the pre-barrier lgkmcnt(0) is satisfied on arrival.
// All 24 dest registers were already live through phase C (VGPR 112), cost ~0.
#define BM2 256
#define BN2 256
#define BK2 64
#define NT  (K_DIM / BK2)   // 64

__global__ __launch_bounds__(512, 2) void gemm256_kernel(
    const __bf16* __restrict__ xb, const __bf16* __restrict__ wb,
    const float* __restrict__ bias, float* __restrict__ out)
{
    __shared__ __align__(16) __bf16 As[2][BM2 * BK2];   // 2 x 32 KiB
    __shared__ __align__(16) __bf16 Bs[2][BN2 * BK2];   // 2 x 32 KiB

    const int tid  = threadIdx.x;
    const int lane = tid & 63;
    const int wid  = tid >> 6;             // 8 waves: 2(M) x 4(N)
    const int wm = (wid >> 2) * 128;
    const int wn = (wid & 3) * 64;

    // XCD-bijective swizzle: grid 688 = 8 * 86
    const int bid = blockIdx.x;
    const int wg  = (bid & 7) * 86 + (bid >> 3);
    const int m0 = (wg / 43) * BM2;
    const int n0 = (wg % 43) * BN2;

    // ---- staging: 4 x 16B chunks per thread per operand per K-tile ----
    const __bf16* pa[4];
    const __bf16* pb[4];
    int chk[4];
    #pragma unroll
    for (int l = 0; l < 4; ++l) {
        const int ch  = l * 512 + tid;         // 0..2047
        const int row = ch >> 3;
        const int g   = (ch & 7) ^ (row & 7);  // involution per row
        chk[l] = ch;
        pa[l] = xb + (size_t)(m0 + row) * K_DIM + g * 8;
        pb[l] = wb + (size_t)(n0 + row) * K_DIM + g * 8;
    }
    lds_u8* baseA = (lds_u8*)&As[0][0];
    lds_u8* baseB = (lds_u8*)&Bs[0][0];

    auto STAGE = [&](int buf, int kofs) {
        lds_u8* dA_ = baseA + buf * (BM2 * BK2 * 2);
        lds_u8* dB_ = baseB + buf * (BN2 * BK2 * 2);
        #pragma unroll
        for (int l = 0; l < 4; ++l)
            __builtin_amdgcn_global_load_lds((g_void*)(pa[l] + kofs),
                                             (lds_void*)(dA_ + chk[l] * 16), 16, 0, 0);
        #pragma unroll
        for (int l = 0; l < 4; ++l)
            __builtin_amdgcn_global_load_lds((g_void*)(pb[l] + kofs),
                                             (lds_void*)(dB_ + chk[l] * 16), 16, 0, 0);
    };

    // ---- fragment read addressing (swizzle folded in) ----
    const int fr  = lane & 15;
    const int fc  = lane >> 4;
    const int swz = fr & 7;
    const int col0 = (fc ^ swz) * 8;           // kk = 0
    const int col1 = ((4 + fc) ^ swz) * 8;     // kk = 1
    const int rowoffA = (wm + fr) * BK2;       // elems
    const int rowoffB = (wn + fr) * BK2;

    f32x4 acc[8][4];
    #pragma unroll
    for (int m = 0; m < 8; ++m)
        #pragma unroll
        for (int n = 0; n < 4; ++n) acc[m][n] = (f32x4){0.f, 0.f, 0.f, 0.f};

    // ---- prologue: tiles 0 and 1 in flight, wait for tile 0 ----
    STAGE(0, 0);
    STAGE(1, BK2);
    asm volatile("s_waitcnt vmcnt(8)" ::: "memory");
    __builtin_amdgcn_sched_barrier(0);
    __builtin_amdgcn_s_barrier();
    __builtin_amdgcn_sched_barrier(0);

    for (int t = 0; t < NT; ++t) {
        const int cur = t & 1;
        const __bf16* ra = &As[0][0] + cur * (BM2 * BK2) + rowoffA;
        const __bf16* rb = &Bs[0][0] + cur * (BN2 * BK2) + rowoffB;
        bf16x8 aR[8], bR[8], a2[8];

        // ---- ALL reads up front, phase-A operands first ----
        #pragma unroll
        for (int n = 0; n < 2; ++n) {                         // bR n0,n1 (phase A)
            bR[n * 2 + 0] = *(const bf16x8*)(rb + n * 1024 + col0);
            bR[n * 2 + 1] = *(const bf16x8*)(rb + n * 1024 + col1);
        }
        #pragma unroll
        for (int m = 0; m < 4; ++m) {                         // aR m0-3 (phase A)
            aR[m * 2 + 0] = *(const bf16x8*)(ra + m * 1024 + col0);
            aR[m * 2 + 1] = *(const bf16x8*)(ra + m * 1024 + col1);
        }
        #pragma unroll
        for (int n = 2; n < 4; ++n) {                         // bR n2,n3 (phase B)
            bR[n * 2 + 0] = *(const bf16x8*)(rb + n * 1024 + col0);
            bR[n * 2 + 1] = *(const bf16x8*)(rb + n * 1024 + col1);
        }
        #pragma unroll
        for (int m = 0; m < 4; ++m) {                         // a2 m4-7 (phase C)
            a2[m * 2 + 0] = *(const bf16x8*)(ra + (m + 4) * 1024 + col0);
            a2[m * 2 + 1] = *(const bf16x8*)(ra + (m + 4) * 1024 + col1);
        }

        // ---- phase A: MFMA quadrant (m0-3, n0-1) ----
        __builtin_amdgcn_s_setprio(1);
        #pragma unroll
        for (int m = 0; m < 4; ++m)
            #pragma unroll
            for (int n = 0; n < 2; ++n)
                #pragma unroll
                for (int kk = 0; kk < 2; ++kk)
                    acc[m][n] = __builtin_amdgcn_mfma_f32_16x16x32_bf16(
                        aR[m * 2 + kk], bR[n * 2 + kk], acc[m][n], 0, 0, 0);
        __builtin_amdgcn_s_setprio(0);

        // ---- phase B: MFMA quadrant (m0-3, n2-3) ----
        __builtin_amdgcn_s_setprio(1);
        #pragma unroll
        for (int m = 0; m < 4; ++m)
            #pragma unroll
            for (int n = 2; n < 4; ++n)
                #pragma unroll
                for (int kk = 0; kk < 2; ++kk)
                    acc[m][n] = __builtin_amdgcn_mfma_f32_16x16x32_bf16(
                        aR[m * 2 + kk], bR[n * 2 + kk], acc[m][n], 0, 0, 0);
        __builtin_amdgcn_s_setprio(0);

        // ---- phase C: drain (no-op by now); barrier; prefetch t+2; MFMA rest ----
        asm volatile("s_waitcnt lgkmcnt(0)" ::: "memory");   // my reads of buf[cur] done
        __builtin_amdgcn_sched_barrier(0);
        __builtin_amdgcn_s_barrier();                        // all waves done reading buf[cur]
        __builtin_amdgcn_sched_barrier(0);
        if (t + 2 < NT) STAGE(cur, (t + 2) * BK2);           // overwrite buf[cur] with tile t+2

        __builtin_amdgcn_s_setprio(1);
        #pragma unroll
        for (int m = 0; m < 4; ++m)
            #pragma unroll
            for (int n = 2; n < 4; ++n)
                #pragma unroll
                for (int kk = 0; kk < 2; ++kk)
                    acc[m + 4][n] = __builtin_amdgcn_mfma_f32_16x16x32_bf16(
                        a2[m * 2 + kk], bR[n * 2 + kk], acc[m + 4][n], 0, 0, 0);
        #pragma unroll
        for (int m = 0; m < 4; ++m)
            #pragma unroll
            for (int n = 0; n < 2; ++n)
                #pragma unroll
                for (int kk = 0; kk < 2; ++kk)
                    acc[m + 4][n] = __builtin_amdgcn_mfma_f32_16x16x32_bf16(
                        a2[m * 2 + kk], bR[n * 2 + kk], acc[m + 4][n], 0, 0, 0);
        __builtin_amdgcn_s_setprio(0);

        // tile t+1 (8 oldest outstanding loads) must be complete before next iter
        if (t + 2 < NT) { asm volatile("s_waitcnt vmcnt(8)" ::: "memory"); }
        else            { asm volatile("s_waitcnt vmcnt(0)" ::: "memory"); }
        __builtin_amdgcn_sched_barrier(0);
        __builtin_amdgcn_s_barrier();
        __builtin_amdgcn_sched_barrier(0);
    }

    // ---- epilogue: C/D layout col=lane&15, row=(lane>>4)*4+r ----
    const int cn  = lane & 15;
    const int cr4 = (lane >> 4) * 4;
    #pragma unroll
    for (int n = 0; n < 4; ++n) {
        const int col = n0 + wn + n * 16 + cn;
        const float bv = bias[col];
        #pragma unroll
        for (int m = 0; m < 8; ++m) {
            const int row = m0 + wm + m * 16 + cr4;
            #pragma unroll
            for (int r = 0; r < 4; ++r)
                out[(size_t)(row + r) * N_DIM + col] = acc[m][n][r] + bv;
        }
    }
}

// ================= fallback: round-1 fused kernel (if ws too small) =================
#define FBM 128
#define FBN 128
#define FBK 32
#define FLDSS 40
__global__ __launch_bounds__(256) void gptq_gemm_fused_kernel(
    const float* __restrict__ x, const int* __restrict__ qw, const int* __restrict__ qz,
    const float* __restrict__ sc, const float* __restrict__ bias, float* __restrict__ out)
{
    __shared__ __align__(16) __bf16 Asm[FBM][FLDSS];
    __shared__ __align__(16) __bf16 Bsm[FBN][FLDSS];
    const int tid = threadIdx.x, lane = tid & 63, wid = tid >> 6;
    const int m0 = blockIdx.y * FBM, n0 = blockIdx.x * FBN;
    const int wm = (wid >> 1) * 64, wn = (wid & 1) * 64;
    f32x4 acc[4][4];
    #pragma unroll
    for (int i = 0; i < 4; ++i)
        #pragma unroll
        for (int j = 0; j < 4; ++j) acc[i][j] = (f32x4){0.f, 0.f, 0.f, 0.f};
    const int a_m = tid >> 2, a_h = tid & 3;
    const int b_n = tid & 127, b_k8 = tid >> 7;
    const int ng = n0 + b_n, zsh = (ng & 7) * 4;
    const int fr = lane & 15, fc = lane >> 4;
    for (int k0 = 0; k0 < K_DIM; k0 += FBK) {
        const int g = k0 >> 7;
        const float* xa = x + (size_t)(m0 + a_m) * K_DIM + k0 + a_h * 8;
        f32x4 a0 = *(const f32x4*)xa;
        f32x4 a1 = *(const f32x4*)(xa + 4);
        const float* xbp = xa + (size_t)64 * K_DIM;
        f32x4 a2 = *(const f32x4*)xbp;
        f32x4 a3 = *(const f32x4*)(xbp + 4);
        const int kb = (k0 >> 3) + b_k8;
        const int w0 = qw[(size_t)kb * N_DIM + ng];
        const int w1 = qw[(size_t)(kb + 2) * N_DIM + ng];
        const float s = sc[(size_t)g * N_DIM + ng];
        const float nzs = -(float)((qz[(size_t)g * (N_DIM / 8) + (ng >> 3)] >> zsh) & 15) * s;
        __syncthreads();
        bf16x8 av0, av1;
        #pragma unroll
        for (int j = 0; j < 4; ++j) {
            av0[j] = f2bf(a0[j]); av0[j + 4] = f2bf(a1[j]);
            av1[j] = f2bf(a2[j]); av1[j + 4] = f2bf(a3[j]);
        }
        *(bf16x8*)&Asm[a_m][a_h * 8] = av0;
        *(bf16x8*)&Asm[a_m + 64][a_h * 8] = av1;
        bf16x8 bv0, bv1;
        #pragma unroll
        for (int j = 0; j < 8; ++j) {
            bv0[j] = f2bf(fmaf((float)((w0 >> (4 * j)) & 15), s, nzs));
            bv1[j] = f2bf(fmaf((float)((w1 >> (4 * j)) & 15), s, nzs));
        }
        *(bf16x8*)&Bsm[b_n][b_k8 * 8] = bv0;
        *(bf16x8*)&Bsm[b_n][(b_k8 + 2) * 8] = bv1;
        __syncthreads();
        bf16x8 af[4], bfr[4];
        #pragma unroll
        for (int i = 0; i < 4; ++i) af[i] = *(const bf16x8*)&Asm[wm + i * 16 + fr][fc * 8];
        #pragma unroll
        for (int j = 0; j < 4; ++j) bfr[j] = *(const bf16x8*)&Bsm[wn + j * 16 + fr][fc * 8];
        #pragma unroll
        for (int i = 0; i < 4; ++i)
            #pragma unroll
            for (int j = 0; j < 4; ++j)
                acc[i][j] = __builtin_amdgcn_mfma_f32_16x16x32_bf16(af[i], bfr[j], acc[i][j], 0, 0, 0);
    }
    const int cn = lane & 15, cr4 = (lane >> 4) * 4;
    #pragma unroll
    for (int j = 0; j < 4; ++j) {
        const int col = n0 + wn + j * 16 + cn;
        const float bv = bias[col];
        #pragma unroll
        for (int i = 0; i < 4; ++i) {
            const int row = m0 + wm + i * 16 + cr4;
            #pragma unroll
            for (int r = 0; r < 4; ++r)
                out[(size_t)(row + r) * N_DIM + col] = acc[i][j][r] + bv;
        }
    }
}

extern "C" void kernel_launch(void* const* d_in, const int* in_sizes, int n_in,
                              void* d_out, int out_size, void* d_ws, size_t ws_size,
                              hipStream_t stream) {
    const float* x    = (const float*)d_in[0];
    const int*   qw   = (const int*)d_in[1];
    const int*   qz   = (const int*)d_in[2];
    const float* sc   = (const float*)d_in[3];
    const float* bias = (const float*)d_in[4];
    float* out = (float*)d_out;
    const int M = in_sizes[0] / K_DIM;   // 4096

    const size_t xb_bytes = (size_t)M * K_DIM * sizeof(__bf16);        // 32 MiB
    const size_t wb_bytes = (size_t)N_DIM * K_DIM * sizeof(__bf16);    // 86 MiB
    if (ws_size >= xb_bytes + wb_bytes && (M % BM2) == 0) {
        __bf16* xb = (__bf16*)d_ws;
        __bf16* wb = (__bf16*)((uint8_t*)d_ws + xb_bytes);
        const int total8 = M * K_DIM / 8;
        cvt_x_kernel<<<dim3(total8 / 256), dim3(256), 0, stream>>>(x, xb, total8);
        dequant_w_kernel<<<dim3(N_DIM / 256, K_DIM / 8 / 8), dim3(256), 0, stream>>>(qw, qz, sc, wb);
        const int nblocks = (N_DIM / BN2) * (M / BM2);   // 43 * 16 = 688
        gemm256_kernel<<<dim3(nblocks), dim3(512), 0, stream>>>(xb, wb, bias, out);
    } else {
        gptq_gemm_fused_kernel<<<dim3(N_DIM / FBN, M / FBM), dim3(256), 0, stream>>>(x, qw, qz, sc, bias, out);
    }
}